// Round 7
// baseline (1361.722 us; speedup 1.0000x reference)
//
#include <hip/hip_runtime.h>

#define TT 2048
#define DD 1024
#define ND3 3072
#define LL 4
#define MAXIT 12
#define NBLK 256

typedef float f32x4 __attribute__((ext_vector_type(4)));
typedef __bf16 bf16x8 __attribute__((ext_vector_type(8)));

__device__ __forceinline__ float sigmoidf_(float x) { return 1.f / (1.f + __expf(-x)); }

__device__ __forceinline__ float gru_out(float xr, float xz, float xn,
                                         float hr, float hz, float hn, float hp)
{
    float rg = sigmoidf_(xr + hr);
    float zg = sigmoidf_(xz + hz);
    float ng = tanhf(xn + rg * hn);
    return (1.f - zg) * ng + zg * hp;
}

__device__ __forceinline__ ushort f2bf(float x)
{
    unsigned u = __builtin_bit_cast(unsigned, x);
    return (ushort)((u + 0x7FFFu + ((u >> 16) & 1u)) >> 16);
}

__device__ __forceinline__ float bf2f(ushort u)
{
    return __builtin_bit_cast(float, ((unsigned)u) << 16);
}

__device__ __forceinline__ void gld_lds16(const void* g, void* l)
{
    __builtin_amdgcn_global_load_lds(
        (const __attribute__((address_space(1))) unsigned int*)g,
        (__attribute__((address_space(3))) unsigned int*)l, 16, 0, 0);
}

// Device-wide barrier. Co-residency guaranteed: 256 blocks on 256 CUs
// (512 thr, <=29.4KB LDS, <=256 VGPR -> every block resident; blocks only
// terminate after the final barrier, so the dispatcher places all 256).
// Monotone arrive counter (zeroed by hipMemsetAsync each call); target =
// phase * NBLK. threadfence gives cross-XCD L2 writeback/invalidate.
__device__ __forceinline__ void bar_sync(unsigned* cnt, unsigned* pctr)
{
    __syncthreads();
    if (threadIdx.x == 0) {
        __threadfence();
        unsigned tgt = (++(*pctr)) * (unsigned)NBLK;
        __hip_atomic_fetch_add(cnt, 1u, __ATOMIC_RELAXED, __HIP_MEMORY_SCOPE_AGENT);
        while (__hip_atomic_load(cnt, __ATOMIC_RELAXED, __HIP_MEMORY_SCOPE_AGENT) < tgt)
            __builtin_amdgcn_s_sleep(2);
        __threadfence();
    }
    __syncthreads();
}

// ---------------------------------------------------------------------------
// Episode segmentation + counting sort (descending length). One block, parallel.
// Emits: g_start, g_len, g_perm, g_nact[0..MAXIT], g_srow[t]=e+1 at starts,
// g_flags[l] = (term[0]==0) && any(h0[l] != 0).
// ---------------------------------------------------------------------------
__global__ __launch_bounds__(256)
void seg_kernel(const int* __restrict__ term, int* __restrict__ g_start,
                int* __restrict__ g_len, int* __restrict__ g_perm,
                int* __restrict__ g_nact, int* __restrict__ g_srow,
                const float* __restrict__ h0, int* __restrict__ g_flags)
{
    __shared__ int s_start[TT + 1];
    __shared__ int s_len[TT];
    __shared__ int s_hist[TT + 1];
    __shared__ int s_base[TT + 1];
    __shared__ int s_p[256];
    __shared__ int s_wsum[33];
    __shared__ int s_n;
    __shared__ int s_f[LL];
    int tid = threadIdx.x, lane = tid & 63, wv = tid >> 6;

    for (int i = tid; i <= TT; i += 256) s_hist[i] = 0;
    for (int i = tid; i < TT; i += 256) g_srow[i] = 0;
    if (tid < LL) s_f[tid] = 0;

    unsigned long long msk[8];
#pragma unroll
    for (int p = 0; p < 8; ++p) {
        int t = p * 256 + tid;
        int bit = (t == 0) || (term[t] != 0);
        unsigned long long m = __ballot(bit);
        msk[p] = m;
        if (lane == 0) s_wsum[p * 4 + wv] = __popcll(m);
    }
    __syncthreads();
    if (tid == 0) {
        int run = 0;
        for (int i = 0; i < 32; ++i) { int v = s_wsum[i]; s_wsum[i] = run; run += v; }
        s_n = run;
    }
    __syncthreads();
    int n = s_n;
#pragma unroll
    for (int p = 0; p < 8; ++p) {
        int t = p * 256 + tid;
        unsigned long long m = msk[p];
        if ((m >> lane) & 1ull) {
            int e = s_wsum[p * 4 + wv] + __popcll(m & ((1ull << lane) - 1ull));
            s_start[e] = t;
        }
    }
    if (tid == 0) s_start[n] = TT;
    __syncthreads();
    for (int e = tid; e < n; e += 256) {
        int L = s_start[e + 1] - s_start[e];
        s_len[e] = L;
        atomicAdd(&s_hist[L], 1);
    }
    // h0 nonzero scan (overlaps with hist barrier needs)
    for (int i = tid; i < LL * DD; i += 256)
        if (h0[i] != 0.f) atomicOr(&s_f[i >> 10], 1);
    __syncthreads();
    int lo = 8 * tid + 1;
    int p_i = 0;
#pragma unroll
    for (int j = 0; j < 8; ++j) p_i += s_hist[lo + j];
    s_p[tid] = p_i;
    __syncthreads();
    if (tid < 64) {
        int q0 = s_p[tid * 4], q1 = s_p[tid * 4 + 1], q2 = s_p[tid * 4 + 2], q3 = s_p[tid * 4 + 3];
        int q = q0 + q1 + q2 + q3;
        int acc = q;
        for (int off = 1; off < 64; off <<= 1) {
            int v = __shfl_down(acc, off);
            if (lane + off < 64) acc += v;
        }
        int ex = acc - q;
        s_p[tid * 4 + 3] = ex;
        s_p[tid * 4 + 2] = ex + q3;
        s_p[tid * 4 + 1] = ex + q3 + q2;
        s_p[tid * 4 + 0] = ex + q3 + q2 + q1;
    }
    __syncthreads();
    int running = s_p[tid];
    for (int j = 7; j >= 0; --j) {
        s_base[lo + j] = running;
        running += s_hist[lo + j];
    }
    __syncthreads();
    if (tid == 0) g_nact[0] = n;
    if (tid >= 1 && tid <= MAXIT) g_nact[tid] = s_base[tid];
    if (tid < LL) g_flags[tid] = (term[0] == 0) ? s_f[tid] : 0;
    __syncthreads();
    for (int e = tid; e < n; e += 256) {
        int st = s_start[e];
        g_start[e] = st;
        g_srow[st] = e + 1;
        int L = s_len[e];
        g_len[e] = L;
        int pos = atomicAdd(&s_base[L], 1);
        g_perm[pos] = e;
    }
}

// ---------------------------------------------------------------------------
// Transpose + cast ALL weight matrices. src [DD][ND3] fp32 -> dst [ND3][DD] bf16.
// ---------------------------------------------------------------------------
__global__ __launch_bounds__(256)
void transcast_all(const float* __restrict__ Wi, const float* __restrict__ Wh,
                   ushort* __restrict__ WT_all, ushort* __restrict__ WhT_all)
{
    int z = blockIdx.z;
    int l = z >> 1;
    const float* src = ((z & 1) ? Wh : Wi) + (size_t)l * DD * ND3;
    ushort* dst = ((z & 1) ? WhT_all : WT_all) + (size_t)l * ND3 * DD;
    __shared__ float tile[64][65];
    int tid = threadIdx.x;
    int n0 = blockIdx.x * 64, k0 = blockIdx.y * 64;
#pragma unroll
    for (int i = 0; i < 16; ++i) {
        int idx = i * 256 + tid;
        int r = idx >> 6, c = idx & 63;
        tile[r][c] = src[(size_t)(k0 + r) * ND3 + n0 + c];
    }
    __syncthreads();
#pragma unroll
    for (int i = 0; i < 4; ++i) {
        int idx = i * 256 + tid;
        int nr = idx >> 4, kq = idx & 15;
        float a0 = tile[kq * 4 + 0][nr];
        float a1 = tile[kq * 4 + 1][nr];
        float a2 = tile[kq * 4 + 2][nr];
        float a3 = tile[kq * 4 + 3][nr];
        ushort4 o;
        o.x = f2bf(a0); o.y = f2bf(a1); o.z = f2bf(a2); o.w = f2bf(a3);
        *(ushort4*)&dst[(size_t)(n0 + nr) * DD + k0 + kq * 4] = o;
    }
}

// ---------------------------------------------------------------------------
struct MegaArgs {
    const float* x_in; const int* term; const float* h0; const float* Wh;
    const float* bh; float* out;
    ushort* xp; float* Hb0; float* Hb1; ushort* Hbf0; ushort* Hbf1;
    ushort* Xbf; ushort* Yb0; ushort* Yb1;
    const ushort* WT_all; const ushort* WhT_all;
    const int* g_start; const int* g_len; const int* g_perm;
    const int* g_nact; const int* g_srow; const int* g_flags;
    unsigned* bar;
};

// gemm + fused it0 phase: one 128(t) x 64(hcol)x3(gate) tile per block.
__device__ void gemm_phase(const ushort* __restrict__ A, const ushort* __restrict__ WT,
                           const float* __restrict__ bh, ushort* __restrict__ xp,
                           float* __restrict__ Hb0, ushort* __restrict__ Hbf0,
                           ushort* __restrict__ ybf, float* __restrict__ yf32,
                           float* __restrict__ finals, const int* __restrict__ g_srow,
                           char* smem)
{
    ushort* As = (ushort*)smem;            // 8 KB
    ushort* Bs = (ushort*)(smem + 8192);   // 12 KB
    int tid = threadIdx.x, lane = tid & 63, wv = tid >> 6;
    int bid = blockIdx.x;
    int m0 = (bid >> 4) * 128, c0 = (bid & 15) * 64;
    int wr = wv >> 1, wc = wv & 1;
    int fr = lane & 15, g = lane >> 4;
    f32x4 acc[2][3][2] = {};

    int ars = tid >> 2;
    int asl = (tid & 3) ^ ((ars >> 1) & 3);
    const ushort* srcA = A + (size_t)(m0 + ars) * DD + asl * 8;
    int j0 = tid >> 2, f0 = j0 >> 6;
    int sl0 = (tid & 3) ^ ((j0 >> 1) & 3);
    const ushort* srcB0 = WT + (size_t)(f0 * DD + c0 + (j0 & 63)) * DD + sl0 * 8;
    int cc1 = 512 + tid, j1 = cc1 >> 2, f1 = j1 >> 6;
    int sl1 = (cc1 & 3) ^ ((j1 >> 1) & 3);
    const ushort* srcB1 = WT + (size_t)(f1 * DD + c0 + (j1 & 63)) * DD + sl1 * 8;

    for (int k0 = 0; k0 < DD; k0 += 32) {
        gld_lds16(srcA + k0, (char*)As + wv * 1024);
        gld_lds16(srcB0 + k0, (char*)Bs + wv * 1024);
        if (tid < 256) gld_lds16(srcB1 + k0, (char*)Bs + 8192 + wv * 1024);
        __syncthreads();

        bf16x8 af[2];
#pragma unroll
        for (int mi = 0; mi < 2; ++mi) {
            int a = wr * 32 + mi * 16 + fr;
            af[mi] = *(const bf16x8*)(As + a * 32 + (g ^ ((a >> 1) & 3)) * 8);
        }
#pragma unroll
        for (int f = 0; f < 3; ++f)
#pragma unroll
            for (int hs = 0; hs < 2; ++hs) {
                int j = f * 64 + wc * 32 + hs * 16 + fr;
                bf16x8 bb = *(const bf16x8*)(Bs + j * 32 + (g ^ ((j >> 1) & 3)) * 8);
#pragma unroll
                for (int mi = 0; mi < 2; ++mi)
                    acc[mi][f][hs] = __builtin_amdgcn_mfma_f32_16x16x32_bf16(
                        af[mi], bb, acc[mi][f][hs], 0, 0, 0);
            }
        __syncthreads();
    }

#pragma unroll
    for (int mi = 0; mi < 2; ++mi)
#pragma unroll
        for (int hs = 0; hs < 2; ++hs) {
            int col = c0 + wc * 32 + hs * 16 + fr;
#pragma unroll
            for (int r2 = 0; r2 < 4; ++r2) {
                int t = m0 + wr * 32 + mi * 16 + g * 4 + r2;
                float xr = acc[mi][0][hs][r2];
                float xz = acc[mi][1][hs][r2];
                float xn = acc[mi][2][hs][r2];
                xp[(size_t)t * ND3 + col] = f2bf(xr);
                xp[(size_t)t * ND3 + DD + col] = f2bf(xz);
                xp[(size_t)t * ND3 + 2 * DD + col] = f2bf(xn);
                int sr = g_srow[t];
                if (sr) {
                    int e = sr - 1;
                    float hnew = gru_out(xr, xz, xn, bh[col], bh[DD + col],
                                         bh[2 * DD + col], 0.f);
                    Hb0[(size_t)e * DD + col] = hnew;
                    Hbf0[(size_t)e * DD + col] = f2bf(hnew);
                    if (yf32) yf32[(size_t)t * DD + col] = hnew;
                    else      ybf[(size_t)t * DD + col] = f2bf(hnew);
                    if (t == TT - 1) finals[col] = hnew;
                }
            }
        }
}

// h0 != 0 fixup for the t==0 episode (episode index 0). Blocks 0..31.
__device__ void fixup_phase(const float* __restrict__ h0g, const ushort* __restrict__ xp,
                            const ushort* __restrict__ WhT, const float* __restrict__ bh,
                            float* __restrict__ Hb0, ushort* __restrict__ Hbf0,
                            ushort* __restrict__ ybf, float* __restrict__ yf32,
                            char* smem)
{
    if (blockIdx.x >= 32) return;
    float* h0s = (float*)smem;              // 4 KB
    float* part = (float*)(smem + 4096);    // [3][32][16] = 6 KB
    int tid = threadIdx.x;
    h0s[tid] = h0g[tid];
    h0s[tid + 512] = h0g[tid + 512];
    __syncthreads();
    int hc = blockIdx.x * 32 + (tid & 31);
    int ks = tid >> 5;   // 0..15 (64-k slices)
#pragma unroll
    for (int f = 0; f < 3; ++f) {
        const ushort* wrow = WhT + (size_t)(f * DD + hc) * DD + ks * 64;
        float acc = 0.f;
        for (int k = 0; k < 64; ++k) acc += h0s[ks * 64 + k] * bf2f(wrow[k]);
        part[(f * 32 + (tid & 31)) * 16 + ks] = acc;
    }
    __syncthreads();
    if (tid < 32) {
        int c = blockIdx.x * 32 + tid;
        float hg[3];
#pragma unroll
        for (int f = 0; f < 3; ++f) {
            float s = 0.f;
#pragma unroll
            for (int j = 0; j < 16; ++j) s += part[(f * 32 + tid) * 16 + j];
            hg[f] = s + bh[f * DD + c];
        }
        float xr = bf2f(xp[c]), xz = bf2f(xp[DD + c]), xn = bf2f(xp[2 * DD + c]);
        float hnew = gru_out(xr, xz, xn, hg[0], hg[1], hg[2], h0s[c]);
        Hb0[c] = hnew;
        Hbf0[c] = f2bf(hnew);
        if (yf32) yf32[c] = hnew; else ybf[c] = f2bf(hnew);
    }
}

// Iteration phase (verified BK=64 LDS-staged structure), grid-stride tiles.
__device__ void iter_phase(int it, int M, const float* __restrict__ Hp,
                           float* __restrict__ Hn, const ushort* __restrict__ Hbfp,
                           ushort* __restrict__ Hbfn, const ushort* __restrict__ xp,
                           const ushort* __restrict__ WhT, const float* __restrict__ bh,
                           ushort* __restrict__ ybf, float* __restrict__ yf32,
                           float* __restrict__ finals, const int* __restrict__ g_start,
                           const int* __restrict__ g_perm, char* smem)
{
    ushort* As = (ushort*)smem;             // 4 KB
    ushort* Bs = (ushort*)(smem + 4096);    // 24 KB
    int* s_e = (int*)(smem + 28672);
    int* s_t = s_e + 32;
    int* s_v = s_t + 32;
    int tid = threadIdx.x, lane = tid & 63, wv = tid >> 6;
    int fr = lane & 15, g = lane >> 4;
    int rw = (wv & 1) * 16, hw = (wv >> 1) * 16;
    int tiles = 16 * ((M + 31) >> 5);

    for (int tt = blockIdx.x; tt < tiles; tt += NBLK) {
        int r0 = (tt >> 4) * 32;
        int c0 = (tt & 15) * 64;

        if (tid < 32) {
            int r = r0 + tid;
            int v = (r < M) ? 1 : 0;
            int e = v ? g_perm[r] : 0;
            s_e[tid] = e;
            s_v[tid] = v;
            s_t[tid] = v ? (g_start[e] + it) : 0;
        }

        const ushort* srcA = Hbfp;
        if (tid < 256) {
            int row = tid >> 3;
            int rr = r0 + row; if (rr > M - 1) rr = M - 1;
            int eA = g_perm[rr];
            int sl = (tid & 7) ^ (row & 7);
            srcA = Hbfp + (size_t)eA * DD + sl * 8;
        }
        const ushort* srcB[3];
#pragma unroll
        for (int p = 0; p < 3; ++p) {
            int c = p * 512 + tid;
            int j = c >> 3;
            int f = j >> 6;
            int coln = c0 + (j & 63);
            int sl = (c & 7) ^ (j & 7);
            srcB[p] = WhT + (size_t)(f * DD + coln) * DD + sl * 8;
        }

        f32x4 acc[3] = {};
        for (int k0 = 0; k0 < DD; k0 += 64) {
            if (tid < 256) gld_lds16(srcA + k0, (char*)As + wv * 1024);
            gld_lds16(srcB[0] + k0, (char*)Bs + wv * 1024);
            gld_lds16(srcB[1] + k0, (char*)Bs + 8192 + wv * 1024);
            gld_lds16(srcB[2] + k0, (char*)Bs + 16384 + wv * 1024);
            __syncthreads();

            int arow = rw + fr;
#pragma unroll
            for (int kw = 0; kw < 2; ++kw) {
                int sA = (kw * 4 + g) ^ (arow & 7);
                bf16x8 af = *(const bf16x8*)(As + arow * 64 + sA * 8);
#pragma unroll
                for (int f = 0; f < 3; ++f) {
                    int jf = f * 64 + hw + fr;
                    int sB = (kw * 4 + g) ^ (jf & 7);
                    bf16x8 bb = *(const bf16x8*)(Bs + jf * 64 + sB * 8);
                    acc[f] = __builtin_amdgcn_mfma_f32_16x16x32_bf16(af, bb, acc[f], 0, 0, 0);
                }
            }
            __syncthreads();
        }

        int col = c0 + hw + fr;
#pragma unroll
        for (int r2 = 0; r2 < 4; ++r2) {
            int row = rw + g * 4 + r2;
            if (!s_v[row]) continue;
            int e = s_e[row], t = s_t[row];
            float hr = acc[0][r2] + bh[col];
            float hz = acc[1][r2] + bh[DD + col];
            float hn = acc[2][r2] + bh[2 * DD + col];
            float xr = bf2f(xp[(size_t)t * ND3 + col]);
            float xz = bf2f(xp[(size_t)t * ND3 + DD + col]);
            float xn = bf2f(xp[(size_t)t * ND3 + 2 * DD + col]);
            float hp = Hp[(size_t)e * DD + col];
            float hnew = gru_out(xr, xz, xn, hr, hz, hn, hp);
            Hn[(size_t)e * DD + col] = hnew;
            Hbfn[(size_t)e * DD + col] = f2bf(hnew);
            if (yf32) yf32[(size_t)t * DD + col] = hnew;
            else      ybf[(size_t)t * DD + col] = f2bf(hnew);
            if (t == TT - 1) finals[col] = hnew;
        }
        __syncthreads();   // protect LDS reuse on next tile
    }
}

// Serial cleanup for episodes longer than MAXIT (rare).
__device__ void cleanup_phase(int Mt, const float* __restrict__ Hlast,
                              const ushort* __restrict__ xp, const float* __restrict__ Wh,
                              const float* __restrict__ bh, ushort* __restrict__ ybf,
                              float* __restrict__ yf32, float* __restrict__ finals,
                              const int* __restrict__ g_start, const int* __restrict__ g_len,
                              const int* __restrict__ g_perm, char* smem)
{
    float* h = (float*)smem;   // 4 KB
    int tid = threadIdx.x;
    for (int r = blockIdx.x; r < Mt; r += NBLK) {
        int e = g_perm[r];
        int s0 = g_start[e];
        int L = g_len[e];
        h[tid] = Hlast[(size_t)e * DD + tid];
        h[tid + 512] = Hlast[(size_t)e * DD + tid + 512];
        __syncthreads();
        for (int i = MAXIT; i < L; ++i) {
            int t = s0 + i;
            float hnew[2];
#pragma unroll
            for (int j = 0; j < 2; ++j) {
                int c = tid + j * 512;
                float hr = bh[c], hz = bh[DD + c], hn = bh[2 * DD + c];
                for (int k = 0; k < DD; ++k) {
                    float hv = h[k];
                    hr += hv * Wh[(size_t)k * ND3 + c];
                    hz += hv * Wh[(size_t)k * ND3 + DD + c];
                    hn += hv * Wh[(size_t)k * ND3 + 2 * DD + c];
                }
                float xr = bf2f(xp[(size_t)t * ND3 + c]);
                float xz = bf2f(xp[(size_t)t * ND3 + DD + c]);
                float xn = bf2f(xp[(size_t)t * ND3 + 2 * DD + c]);
                hnew[j] = gru_out(xr, xz, xn, hr, hz, hn, h[c]);
                if (yf32) yf32[(size_t)t * DD + c] = hnew[j];
                else      ybf[(size_t)t * DD + c] = f2bf(hnew[j]);
                if (t == TT - 1) finals[c] = hnew[j];
            }
            __syncthreads();
            h[tid] = hnew[0];
            h[tid + 512] = hnew[1];
            __syncthreads();
        }
        __syncthreads();
    }
}

// ---------------------------------------------------------------------------
__global__ __launch_bounds__(512)
void mega_kernel(MegaArgs a)
{
    __shared__ __align__(16) char smem[29440];
    unsigned pctr = 0;
    int bid = blockIdx.x, tid = threadIdx.x;

    // phase: cast x -> bf16
    for (int i = bid * 512 + tid; i < TT * DD / 4; i += NBLK * 512) {
        float4 v = *(const float4*)(a.x_in + (size_t)i * 4);
        ushort4 o;
        o.x = f2bf(v.x); o.y = f2bf(v.y); o.z = f2bf(v.z); o.w = f2bf(v.w);
        *(ushort4*)(a.Xbf + (size_t)i * 4) = o;
    }
    bar_sync(a.bar, &pctr);

    for (int l = 0; l < LL; ++l) {
        const ushort* WTl  = a.WT_all  + (size_t)l * ND3 * DD;
        const ushort* WhTl = a.WhT_all + (size_t)l * ND3 * DD;
        const float*  Whl  = a.Wh + (size_t)l * DD * ND3;
        const float*  bhl  = a.bh + (size_t)l * ND3;
        const ushort* Abf  = (l == 0) ? a.Xbf : ((l == 2) ? a.Yb1 : a.Yb0);
        ushort* ybf  = (l == 0) ? a.Yb0 : ((l == 1) ? a.Yb1 : ((l == 2) ? a.Yb0 : nullptr));
        float*  yf32 = (l == LL - 1) ? a.out : nullptr;
        float*  finals = a.out + (size_t)TT * DD + (size_t)l * DD;

        gemm_phase(Abf, WTl, bhl, a.xp, a.Hb0, a.Hbf0, ybf, yf32, finals,
                   a.g_srow, smem);
        bar_sync(a.bar, &pctr);

        if (a.g_flags[l]) {   // uniform
            fixup_phase(a.h0 + (size_t)l * DD, a.xp, WhTl, bhl, a.Hb0, a.Hbf0,
                        ybf, yf32, smem);
            bar_sync(a.bar, &pctr);
        }

        for (int it = 1; it < MAXIT; ++it) {
            int M = a.g_nact[it];   // uniform
            if (M == 0) break;
            float*  Hp   = (it & 1) ? a.Hb0 : a.Hb1;
            float*  Hn   = (it & 1) ? a.Hb1 : a.Hb0;
            ushort* Hbfp = (it & 1) ? a.Hbf0 : a.Hbf1;
            ushort* Hbfn = (it & 1) ? a.Hbf1 : a.Hbf0;
            iter_phase(it, M, Hp, Hn, Hbfp, Hbfn, a.xp, WhTl, bhl,
                       ybf, yf32, finals, a.g_start, a.g_perm, smem);
            bar_sync(a.bar, &pctr);
        }

        int Mt = a.g_nact[MAXIT];   // uniform
        if (Mt > 0) {
            float* Hlast = ((MAXIT - 1) & 1) ? a.Hb1 : a.Hb0;
            cleanup_phase(Mt, Hlast, a.xp, Whl, bhl, ybf, yf32, finals,
                          a.g_start, a.g_len, a.g_perm, smem);
            bar_sync(a.bar, &pctr);
        }
    }
}

// ---------------------------------------------------------------------------
extern "C" void kernel_launch(void* const* d_in, const int* in_sizes, int n_in,
                              void* d_out, int out_size, void* d_ws, size_t ws_size,
                              hipStream_t stream)
{
    const float* x_in = (const float*)d_in[0];
    const int*   term = (const int*)d_in[1];
    const float* h0   = (const float*)d_in[2];
    const float* Wi   = (const float*)d_in[3];
    const float* Wh   = (const float*)d_in[4];
    const float* bh   = (const float*)d_in[5];
    float* out = (float*)d_out;

    ushort* xp      = (ushort*)d_ws;                      // TT*ND3 bf16
    float*  Hb0     = (float*)(xp + (size_t)TT * ND3);    // TT*DD fp32
    float*  Hb1     = Hb0 + (size_t)TT * DD;              // TT*DD fp32
    ushort* Hbf0    = (ushort*)(Hb1 + (size_t)TT * DD);   // TT*DD bf16
    ushort* Hbf1    = Hbf0 + (size_t)TT * DD;             // TT*DD bf16
    ushort* Xbf     = Hbf1 + (size_t)TT * DD;             // TT*DD bf16
    ushort* Yb0     = Xbf + (size_t)TT * DD;              // TT*DD bf16
    ushort* Yb1     = Yb0 + (size_t)TT * DD;              // TT*DD bf16
    ushort* WT_all  = Yb1 + (size_t)TT * DD;              // LL*ND3*DD bf16
    ushort* WhT_all = WT_all + (size_t)LL * ND3 * DD;     // LL*ND3*DD bf16
    int* ib      = (int*)(WhT_all + (size_t)LL * ND3 * DD);
    int* g_start = ib;                 // TT
    int* g_len   = ib + TT;            // TT
    int* g_perm  = ib + 2 * TT;        // TT
    int* g_nact  = ib + 3 * TT;        // 64
    int* g_srow  = ib + 3 * TT + 64;   // TT
    int* g_flags = ib + 4 * TT + 64;   // 16
    unsigned* bar = (unsigned*)(ib + 4 * TT + 80);

    hipMemsetAsync(bar, 0, sizeof(unsigned), stream);
    seg_kernel<<<1, 256, 0, stream>>>(term, g_start, g_len, g_perm, g_nact,
                                      g_srow, h0, g_flags);
    transcast_all<<<dim3(ND3 / 64, DD / 64, 2 * LL), 256, 0, stream>>>(
        Wi, Wh, WT_all, WhT_all);

    MegaArgs margs;
    margs.x_in = x_in; margs.term = term; margs.h0 = h0; margs.Wh = Wh;
    margs.bh = bh; margs.out = out;
    margs.xp = xp; margs.Hb0 = Hb0; margs.Hb1 = Hb1;
    margs.Hbf0 = Hbf0; margs.Hbf1 = Hbf1;
    margs.Xbf = Xbf; margs.Yb0 = Yb0; margs.Yb1 = Yb1;
    margs.WT_all = WT_all; margs.WhT_all = WhT_all;
    margs.g_start = g_start; margs.g_len = g_len; margs.g_perm = g_perm;
    margs.g_nact = g_nact; margs.g_srow = g_srow; margs.g_flags = g_flags;
    margs.bar = bar;

    mega_kernel<<<dim3(NBLK), dim3(512), 0, stream>>>(margs);
}

// Round 8
// 669.812 us; speedup vs baseline: 2.0330x; 2.0330x over previous
//
#include <hip/hip_runtime.h>

#define TT 2048
#define DD 1024
#define ND3 3072
#define LL 4
#define MAXIT 12
#define NBLK 256
#define BSLOT 544   // uints per barrier slot: 16 subs * 32 + root

typedef float f32x4 __attribute__((ext_vector_type(4)));
typedef __bf16 bf16x8 __attribute__((ext_vector_type(8)));

__device__ __forceinline__ float sigmoidf_(float x) { return 1.f / (1.f + __expf(-x)); }

__device__ __forceinline__ float gru_out(float xr, float xz, float xn,
                                         float hr, float hz, float hn, float hp)
{
    float rg = sigmoidf_(xr + hr);
    float zg = sigmoidf_(xz + hz);
    float ng = tanhf(xn + rg * hn);
    return (1.f - zg) * ng + zg * hp;
}

__device__ __forceinline__ ushort f2bf(float x)
{
    unsigned u = __builtin_bit_cast(unsigned, x);
    return (ushort)((u + 0x7FFFu + ((u >> 16) & 1u)) >> 16);
}

__device__ __forceinline__ float bf2f(ushort u)
{
    return __builtin_bit_cast(float, ((unsigned)u) << 16);
}

__device__ __forceinline__ void gld_lds16(const void* g, void* l)
{
    __builtin_amdgcn_global_load_lds(
        (const __attribute__((address_space(1))) unsigned int*)g,
        (__attribute__((address_space(3))) unsigned int*)l, 16, 0, 0);
}

// ---------------------------------------------------------------------------
// Fence-free device barrier. One slot per sync point (never reused), so no
// reset races. 16 sub-counters (128B apart) -> root. All data that crosses
// this barrier is accessed with agent-scope atomics (sc0/sc1, LLC-coherent),
// so no L2 writeback/invalidate is needed -- no __threadfence anywhere.
// ---------------------------------------------------------------------------
__device__ __forceinline__ void pb_bar(unsigned* slot)
{
    __syncthreads();   // drains vmcnt: this block's sc-stores have reached LLC
    if (threadIdx.x == 0) {
        unsigned old = __hip_atomic_fetch_add(slot + (blockIdx.x & 15) * 32, 1u,
                                              __ATOMIC_RELAXED, __HIP_MEMORY_SCOPE_AGENT);
        if (old == 15u)
            __hip_atomic_fetch_add(slot + 512, 1u, __ATOMIC_RELAXED,
                                   __HIP_MEMORY_SCOPE_AGENT);
        while (__hip_atomic_load(slot + 512, __ATOMIC_RELAXED,
                                 __HIP_MEMORY_SCOPE_AGENT) < 16u)
            __builtin_amdgcn_s_sleep(4);
    }
    __syncthreads();
}

// ---------------------------------------------------------------------------
// Episode segmentation + counting sort (descending length). One block, parallel.
// ---------------------------------------------------------------------------
__global__ __launch_bounds__(256)
void seg_kernel(const int* __restrict__ term, int* __restrict__ g_start,
                int* __restrict__ g_len, int* __restrict__ g_perm,
                int* __restrict__ g_nact)
{
    __shared__ int s_start[TT + 1];
    __shared__ int s_len[TT];
    __shared__ int s_hist[TT + 1];
    __shared__ int s_base[TT + 1];
    __shared__ int s_p[256];
    __shared__ int s_wsum[33];
    __shared__ int s_n;
    int tid = threadIdx.x, lane = tid & 63, wv = tid >> 6;

    for (int i = tid; i <= TT; i += 256) s_hist[i] = 0;

    unsigned long long msk[8];
#pragma unroll
    for (int p = 0; p < 8; ++p) {
        int t = p * 256 + tid;
        int bit = (t == 0) || (term[t] != 0);
        unsigned long long m = __ballot(bit);
        msk[p] = m;
        if (lane == 0) s_wsum[p * 4 + wv] = __popcll(m);
    }
    __syncthreads();
    if (tid == 0) {
        int run = 0;
        for (int i = 0; i < 32; ++i) { int v = s_wsum[i]; s_wsum[i] = run; run += v; }
        s_n = run;
    }
    __syncthreads();
    int n = s_n;
#pragma unroll
    for (int p = 0; p < 8; ++p) {
        int t = p * 256 + tid;
        unsigned long long m = msk[p];
        if ((m >> lane) & 1ull) {
            int e = s_wsum[p * 4 + wv] + __popcll(m & ((1ull << lane) - 1ull));
            s_start[e] = t;
        }
    }
    if (tid == 0) s_start[n] = TT;
    __syncthreads();
    for (int e = tid; e < n; e += 256) {
        int L = s_start[e + 1] - s_start[e];
        s_len[e] = L;
        atomicAdd(&s_hist[L], 1);
    }
    __syncthreads();
    int lo = 8 * tid + 1;
    int p_i = 0;
#pragma unroll
    for (int j = 0; j < 8; ++j) p_i += s_hist[lo + j];
    s_p[tid] = p_i;
    __syncthreads();
    if (tid < 64) {
        int q0 = s_p[tid * 4], q1 = s_p[tid * 4 + 1], q2 = s_p[tid * 4 + 2], q3 = s_p[tid * 4 + 3];
        int q = q0 + q1 + q2 + q3;
        int acc = q;
        for (int off = 1; off < 64; off <<= 1) {
            int v = __shfl_down(acc, off);
            if (lane + off < 64) acc += v;
        }
        int ex = acc - q;
        s_p[tid * 4 + 3] = ex;
        s_p[tid * 4 + 2] = ex + q3;
        s_p[tid * 4 + 1] = ex + q3 + q2;
        s_p[tid * 4 + 0] = ex + q3 + q2 + q1;
    }
    __syncthreads();
    int running = s_p[tid];
    for (int j = 7; j >= 0; --j) {
        s_base[lo + j] = running;
        running += s_hist[lo + j];
    }
    __syncthreads();
    if (tid == 0) g_nact[0] = n;
    if (tid >= 1 && tid <= MAXIT) g_nact[tid] = s_base[tid];
    __syncthreads();
    for (int e = tid; e < n; e += 256) {
        g_start[e] = s_start[e];
        int L = s_len[e];
        g_len[e] = L;
        int pos = atomicAdd(&s_base[L], 1);
        g_perm[pos] = e;
    }
}

// ---------------------------------------------------------------------------
__global__ __launch_bounds__(256)
void cast_bf(const float* __restrict__ src, ushort* __restrict__ dst, int n)
{
    int base = (blockIdx.x * 256 + threadIdx.x) * 4;
    if (base < n) {
        float4 v = *(const float4*)(src + base);
        ushort4 o;
        o.x = f2bf(v.x); o.y = f2bf(v.y); o.z = f2bf(v.z); o.w = f2bf(v.w);
        *(ushort4*)(dst + base) = o;
    }
}

// ---------------------------------------------------------------------------
// Transpose + cast ALL weight matrices (verbatim round 5).
// ---------------------------------------------------------------------------
__global__ __launch_bounds__(256)
void transcast_all(const float* __restrict__ Wi, const float* __restrict__ Wh,
                   ushort* __restrict__ WT_all, ushort* __restrict__ WhT_all)
{
    int z = blockIdx.z;
    int l = z >> 1;
    const float* src = ((z & 1) ? Wh : Wi) + (size_t)l * DD * ND3;
    ushort* dst = ((z & 1) ? WhT_all : WT_all) + (size_t)l * ND3 * DD;
    __shared__ float tile[64][65];
    int tid = threadIdx.x;
    int n0 = blockIdx.x * 64, k0 = blockIdx.y * 64;
#pragma unroll
    for (int i = 0; i < 16; ++i) {
        int idx = i * 256 + tid;
        int r = idx >> 6, c = idx & 63;
        tile[r][c] = src[(size_t)(k0 + r) * ND3 + n0 + c];
    }
    __syncthreads();
#pragma unroll
    for (int i = 0; i < 4; ++i) {
        int idx = i * 256 + tid;
        int nr = idx >> 4, kq = idx & 15;
        float a0 = tile[kq * 4 + 0][nr];
        float a1 = tile[kq * 4 + 1][nr];
        float a2 = tile[kq * 4 + 2][nr];
        float a3 = tile[kq * 4 + 3][nr];
        ushort4 o;
        o.x = f2bf(a0); o.y = f2bf(a1); o.z = f2bf(a2); o.w = f2bf(a3);
        *(ushort4*)&dst[(size_t)(n0 + nr) * DD + k0 + kq * 4] = o;
    }
}

// ---------------------------------------------------------------------------
// Phase A GEMM (verbatim round 5, verified).
// ---------------------------------------------------------------------------
__global__ __launch_bounds__(256)
void gemm_mfma(const ushort* __restrict__ A, const ushort* __restrict__ BT,
               ushort* __restrict__ C)
{
    __shared__ __align__(16) ushort As[128 * 32];
    __shared__ __align__(16) ushort Bs[128 * 32];
    int tid = threadIdx.x, lane = tid & 63, wv = tid >> 6;
    int m0 = blockIdx.y * 128, n0 = blockIdx.x * 128;
    int wr = wv >> 1, wc = wv & 1;
    f32x4 acc[4][4] = {};

    int ci0 = tid, ci1 = 256 + tid;
    int r0s = ci0 >> 2, r1s = ci1 >> 2;
    int ss0 = (ci0 & 3) ^ ((r0s >> 1) & 3);
    int ss1 = (ci1 & 3) ^ ((r1s >> 1) & 3);
    const ushort* Ar0 = A + (size_t)(m0 + r0s) * DD + ss0 * 8;
    const ushort* Ar1 = A + (size_t)(m0 + r1s) * DD + ss1 * 8;
    const ushort* Br0 = BT + (size_t)(n0 + r0s) * DD + ss0 * 8;
    const ushort* Br1 = BT + (size_t)(n0 + r1s) * DD + ss1 * 8;

    int g = lane >> 4, fr = lane & 15;

    for (int k0 = 0; k0 < DD; k0 += 32) {
        gld_lds16(Ar0 + k0, (char*)As + wv * 1024);
        gld_lds16(Ar1 + k0, (char*)As + 4096 + wv * 1024);
        gld_lds16(Br0 + k0, (char*)Bs + wv * 1024);
        gld_lds16(Br1 + k0, (char*)Bs + 4096 + wv * 1024);
        __syncthreads();

        bf16x8 af[4], bb[4];
#pragma unroll
        for (int mi = 0; mi < 4; ++mi) {
            int row = wr * 64 + mi * 16 + fr;
            int slot = g ^ ((row >> 1) & 3);
            af[mi] = *(const bf16x8*)(As + row * 32 + slot * 8);
        }
#pragma unroll
        for (int ni = 0; ni < 4; ++ni) {
            int row = wc * 64 + ni * 16 + fr;
            int slot = g ^ ((row >> 1) & 3);
            bb[ni] = *(const bf16x8*)(Bs + row * 32 + slot * 8);
        }
#pragma unroll
        for (int mi = 0; mi < 4; ++mi)
#pragma unroll
            for (int ni = 0; ni < 4; ++ni)
                acc[mi][ni] = __builtin_amdgcn_mfma_f32_16x16x32_bf16(
                    af[mi], bb[ni], acc[mi][ni], 0, 0, 0);
        __syncthreads();
    }

    int orow = (lane >> 4) * 4, ocol = lane & 15;
#pragma unroll
    for (int mi = 0; mi < 4; ++mi)
#pragma unroll
        for (int ni = 0; ni < 4; ++ni)
#pragma unroll
            for (int r2 = 0; r2 < 4; ++r2)
                C[(size_t)(m0 + wr * 64 + mi * 16 + orow + r2) * ND3 +
                  n0 + wc * 64 + ni * 16 + ocol] = f2bf(acc[mi][ni][r2]);
}

// ---------------------------------------------------------------------------
// Iteration 0 (verbatim round 5).
// ---------------------------------------------------------------------------
__global__ __launch_bounds__(256)
void it0_kernel(const ushort* __restrict__ xp, const float* __restrict__ Wh,
                const float* __restrict__ bh, const float* __restrict__ h0g,
                const int* __restrict__ term, float* __restrict__ Hnext,
                ushort* __restrict__ Hbfn, ushort* __restrict__ ybf,
                float* __restrict__ yf32, float* __restrict__ finals,
                const int* __restrict__ g_start, const int* __restrict__ g_perm,
                const int* __restrict__ g_nact)
{
    int M = g_nact[0];
    int r = blockIdx.x;
    if (r >= M) return;
    int e = g_perm[r];
    int t = g_start[e];
    int tid = threadIdx.x;
    bool useh0 = (t == 0) && (term[0] == 0);
    __shared__ float h0s[DD];
    __shared__ int s_nz;
    if (tid == 0) s_nz = 0;
    __syncthreads();
    if (useh0) {
        int nz = 0;
#pragma unroll
        for (int j = 0; j < 4; ++j) {
            float v = h0g[tid + j * 256];
            h0s[tid + j * 256] = v;
            nz |= (v != 0.f) ? 1 : 0;
        }
        if (nz) atomicOr(&s_nz, 1);
    }
    __syncthreads();
    bool gemv = useh0 && (s_nz != 0);
#pragma unroll
    for (int j = 0; j < 4; ++j) {
        int c = tid + j * 256;
        float hr = bh[c], hz = bh[DD + c], hn = bh[2 * DD + c];
        if (gemv) {
            for (int k = 0; k < DD; ++k) {
                float hv = h0s[k];
                hr += hv * Wh[(size_t)k * ND3 + c];
                hz += hv * Wh[(size_t)k * ND3 + DD + c];
                hn += hv * Wh[(size_t)k * ND3 + 2 * DD + c];
            }
        }
        float hp = useh0 ? h0s[c] : 0.f;
        float xr = bf2f(xp[(size_t)t * ND3 + c]);
        float xz = bf2f(xp[(size_t)t * ND3 + DD + c]);
        float xn = bf2f(xp[(size_t)t * ND3 + 2 * DD + c]);
        float hnew = gru_out(xr, xz, xn, hr, hz, hn, hp);
        Hnext[(size_t)e * DD + c] = hnew;
        Hbfn[(size_t)e * DD + c] = f2bf(hnew);
        if (yf32) yf32[(size_t)t * DD + c] = hnew;
        else      ybf[(size_t)t * DD + c] = f2bf(hnew);
        if (t == TT - 1) finals[c] = hnew;
    }
}

// ---------------------------------------------------------------------------
// Phase B fused: ALL iterations 1..MAXIT-1 in one launch; fence-free barriers
// between iterations. H/Hbf cross barriers via agent-scope (LLC) atomics;
// A-strip preloaded to registers up-front (16 x 8B); B via global_load_lds.
// Tile/fragment/swizzle structure identical to the verified round-5 iter_mfma.
// ---------------------------------------------------------------------------
__global__ __launch_bounds__(512)
void phaseb_kernel(float* __restrict__ Hb0, float* __restrict__ Hb1,
                   ushort* __restrict__ Hbf0, ushort* __restrict__ Hbf1,
                   const ushort* __restrict__ xp, const ushort* __restrict__ WhT,
                   const float* __restrict__ bh, ushort* __restrict__ ybf,
                   float* __restrict__ yf32, float* __restrict__ finals,
                   const int* __restrict__ g_start, const int* __restrict__ g_perm,
                   const int* __restrict__ g_nact, unsigned* __restrict__ barws)
{
    __shared__ __align__(16) ushort As[32 * 64];    // 4 KB
    __shared__ __align__(16) ushort Bs[192 * 64];   // 24 KB
    __shared__ int s_e[32], s_t[32], s_v[32];
    int tid = threadIdx.x, lane = tid & 63, wv = tid >> 6;
    int fr = lane & 15, g = lane >> 4;
    int rw = (wv & 1) * 16, hw = (wv >> 1) * 16;

    for (int it = 1; it < MAXIT; ++it) {
        int M = g_nact[it];   // uniform, read-only
        if (M == 0) break;
        float*  Hp   = (it & 1) ? Hb0 : Hb1;
        float*  Hn   = (it & 1) ? Hb1 : Hb0;
        ushort* Hbfp = (it & 1) ? Hbf0 : Hbf1;
        ushort* Hbfn = (it & 1) ? Hbf1 : Hbf0;
        int tiles = 16 * ((M + 31) >> 5);

        for (int tt = blockIdx.x; tt < tiles; tt += NBLK) {
            int r0 = (tt >> 4) * 32;
            int c0 = (tt & 15) * 64;

            __syncthreads();   // LDS reuse guard (s_e/As/Bs from prior tile)
            if (tid < 32) {
                int r = r0 + tid;
                int v = (r < M) ? 1 : 0;
                int e = v ? g_perm[r] : 0;
                s_e[tid] = e;
                s_v[tid] = v;
                s_t[tid] = v ? (g_start[e] + it) : 0;
            }

            // A-strip: thread = 8B chunk (row = tid>>4, s8 = tid&15); preload
            // whole K into registers via LLC-coherent loads; linear global,
            // swizzled LDS write (slot16 = (s8>>1) ^ (row&7)).
            int arowi = tid >> 4;
            int rr = r0 + arowi; if (rr > M - 1) rr = M - 1;
            int eA = g_perm[rr];
            int s8 = tid & 15;
            const unsigned long long* srcA8 =
                (const unsigned long long*)(Hbfp + (size_t)eA * DD) + s8;
            int dstb = arowi * 128 + ((((s8 >> 1) ^ (arowi & 7)) << 1) | (s8 & 1)) * 8;
            unsigned long long areg[16];
#pragma unroll
            for (int kk = 0; kk < 16; ++kk)
                areg[kk] = __hip_atomic_load(srcA8 + kk * 16, __ATOMIC_RELAXED,
                                             __HIP_MEMORY_SCOPE_AGENT);

            // B staging sources (verbatim round 5, pre-swizzled global)
            const ushort* srcB[3];
#pragma unroll
            for (int p = 0; p < 3; ++p) {
                int c = p * 512 + tid;
                int j = c >> 3;
                int f = j >> 6;
                int coln = c0 + (j & 63);
                int sl = (c & 7) ^ (j & 7);
                srcB[p] = WhT + (size_t)(f * DD + coln) * DD + sl * 8;
            }

            f32x4 acc[3] = {};
#pragma unroll
            for (int kk = 0; kk < 16; ++kk) {
                int k0 = kk * 64;
                gld_lds16(srcB[0] + k0, (char*)Bs + wv * 1024);
                gld_lds16(srcB[1] + k0, (char*)Bs + 8192 + wv * 1024);
                gld_lds16(srcB[2] + k0, (char*)Bs + 16384 + wv * 1024);
                *(unsigned long long*)((char*)As + dstb) = areg[kk];
                __syncthreads();

                int arow = rw + fr;
#pragma unroll
                for (int kw = 0; kw < 2; ++kw) {
                    int sA = (kw * 4 + g) ^ (arow & 7);
                    bf16x8 af = *(const bf16x8*)(As + arow * 64 + sA * 8);
#pragma unroll
                    for (int f = 0; f < 3; ++f) {
                        int jf = f * 64 + hw + fr;
                        int sB = (kw * 4 + g) ^ (jf & 7);
                        bf16x8 bb = *(const bf16x8*)(Bs + jf * 64 + sB * 8);
                        acc[f] = __builtin_amdgcn_mfma_f32_16x16x32_bf16(af, bb, acc[f], 0, 0, 0);
                    }
                }
                __syncthreads();
            }

            int col = c0 + hw + fr;
#pragma unroll
            for (int r2 = 0; r2 < 4; ++r2) {
                int row = rw + g * 4 + r2;
                if (!s_v[row]) continue;   // uniform across the fr^1 pair
                int e = s_e[row], t = s_t[row];
                float hr = acc[0][r2] + bh[col];
                float hz = acc[1][r2] + bh[DD + col];
                float hn = acc[2][r2] + bh[2 * DD + col];
                float xr = bf2f(xp[(size_t)t * ND3 + col]);
                float xz = bf2f(xp[(size_t)t * ND3 + DD + col]);
                float xn = bf2f(xp[(size_t)t * ND3 + 2 * DD + col]);
                float hp = __hip_atomic_load(Hp + (size_t)e * DD + col,
                                             __ATOMIC_RELAXED, __HIP_MEMORY_SCOPE_AGENT);
                float hnew = gru_out(xr, xz, xn, hr, hz, hn, hp);
                __hip_atomic_store(Hn + (size_t)e * DD + col, hnew,
                                   __ATOMIC_RELAXED, __HIP_MEMORY_SCOPE_AGENT);
                ushort mybf = f2bf(hnew);
                unsigned other = __shfl_xor((unsigned)mybf, 1);
                if ((fr & 1) == 0)
                    __hip_atomic_store((unsigned*)(Hbfn + (size_t)e * DD + col),
                                       (unsigned)mybf | (other << 16),
                                       __ATOMIC_RELAXED, __HIP_MEMORY_SCOPE_AGENT);
                if (yf32) yf32[(size_t)t * DD + col] = hnew;
                else      ybf[(size_t)t * DD + col] = mybf;
                if (t == TT - 1) finals[col] = hnew;
            }
        }

        pb_bar(barws + (size_t)(it - 1) * BSLOT);
    }
}

// ---------------------------------------------------------------------------
// Cleanup (verbatim round 5).
// ---------------------------------------------------------------------------
__global__ __launch_bounds__(256)
void cleanup_kernel(const float* __restrict__ Hlast, const ushort* __restrict__ xp,
                    const float* __restrict__ Wh, const float* __restrict__ bh,
                    ushort* __restrict__ ybf, float* __restrict__ yf32,
                    float* __restrict__ finals, const int* __restrict__ g_start,
                    const int* __restrict__ g_len, const int* __restrict__ g_perm,
                    const int* __restrict__ g_nact)
{
    int Mt = g_nact[MAXIT];
    if (Mt == 0) return;
    __shared__ float h[DD];
    int tid = threadIdx.x;
    for (int r = blockIdx.x; r < Mt; r += gridDim.x) {
        int e = g_perm[r];
        int s0 = g_start[e];
        int L = g_len[e];
#pragma unroll
        for (int j = 0; j < 4; ++j) h[tid + j * 256] = Hlast[(size_t)e * DD + tid + j * 256];
        __syncthreads();
        for (int i = MAXIT; i < L; ++i) {
            int t = s0 + i;
            float hnew[4];
#pragma unroll
            for (int j = 0; j < 4; ++j) {
                int c = tid + j * 256;
                float hr = bh[c], hz = bh[DD + c], hn = bh[2 * DD + c];
                for (int k = 0; k < DD; ++k) {
                    float hv = h[k];
                    hr += hv * Wh[(size_t)k * ND3 + c];
                    hz += hv * Wh[(size_t)k * ND3 + DD + c];
                    hn += hv * Wh[(size_t)k * ND3 + 2 * DD + c];
                }
                float xr = bf2f(xp[(size_t)t * ND3 + c]);
                float xz = bf2f(xp[(size_t)t * ND3 + DD + c]);
                float xn = bf2f(xp[(size_t)t * ND3 + 2 * DD + c]);
                float hp = h[c];
                hnew[j] = gru_out(xr, xz, xn, hr, hz, hn, hp);
                if (yf32) yf32[(size_t)t * DD + c] = hnew[j];
                else      ybf[(size_t)t * DD + c] = f2bf(hnew[j]);
                if (t == TT - 1) finals[c] = hnew[j];
            }
            __syncthreads();
#pragma unroll
            for (int j = 0; j < 4; ++j) h[tid + j * 256] = hnew[j];
            __syncthreads();
        }
        __syncthreads();
    }
}

// ---------------------------------------------------------------------------
extern "C" void kernel_launch(void* const* d_in, const int* in_sizes, int n_in,
                              void* d_out, int out_size, void* d_ws, size_t ws_size,
                              hipStream_t stream)
{
    const float* x_in = (const float*)d_in[0];
    const int*   term = (const int*)d_in[1];
    const float* h0   = (const float*)d_in[2];
    const float* Wi   = (const float*)d_in[3];
    const float* Wh   = (const float*)d_in[4];
    const float* bh   = (const float*)d_in[5];
    float* out = (float*)d_out;

    ushort* xp      = (ushort*)d_ws;                      // TT*ND3 bf16
    float*  Hb0     = (float*)(xp + (size_t)TT * ND3);    // TT*DD fp32
    float*  Hb1     = Hb0 + (size_t)TT * DD;              // TT*DD fp32
    ushort* Hbf0    = (ushort*)(Hb1 + (size_t)TT * DD);   // TT*DD bf16
    ushort* Hbf1    = Hbf0 + (size_t)TT * DD;             // TT*DD bf16
    ushort* Xbf     = Hbf1 + (size_t)TT * DD;             // TT*DD bf16
    ushort* Yb0     = Xbf + (size_t)TT * DD;              // TT*DD bf16
    ushort* Yb1     = Yb0 + (size_t)TT * DD;              // TT*DD bf16
    ushort* WT_all  = Yb1 + (size_t)TT * DD;              // LL*ND3*DD bf16
    ushort* WhT_all = WT_all + (size_t)LL * ND3 * DD;     // LL*ND3*DD bf16
    int* ib      = (int*)(WhT_all + (size_t)LL * ND3 * DD);
    int* g_start = ib;                 // TT
    int* g_len   = ib + TT;            // TT
    int* g_perm  = ib + 2 * TT;        // TT
    int* g_nact  = ib + 3 * TT;        // 64
    unsigned* barws = (unsigned*)(ib + 3 * TT + 64);   // LL*(MAXIT-1)*BSLOT

    hipMemsetAsync(barws, 0, (size_t)LL * (MAXIT - 1) * BSLOT * sizeof(unsigned), stream);
    seg_kernel<<<1, 256, 0, stream>>>(term, g_start, g_len, g_perm, g_nact);
    cast_bf<<<(TT * DD / 4 + 255) / 256, 256, 0, stream>>>(x_in, Xbf, TT * DD);
    transcast_all<<<dim3(ND3 / 64, DD / 64, 2 * LL), 256, 0, stream>>>(
        Wi, Wh, WT_all, WhT_all);

    const ushort* Abf[4] = { Xbf, Yb0, Yb1, Yb0 };
    ushort*       Ybo[4] = { Yb0, Yb1, Yb0, nullptr };

    for (int l = 0; l < LL; ++l) {
        const float* Whl = Wh + (size_t)l * DD * ND3;
        const float* bhl = bh + (size_t)l * ND3;
        const ushort* WTl  = WT_all + (size_t)l * ND3 * DD;
        const ushort* WhTl = WhT_all + (size_t)l * ND3 * DD;
        float* yf32 = (l == LL - 1) ? out : nullptr;
        ushort* ybf = Ybo[l];
        float* finals = out + (size_t)TT * DD + (size_t)l * DD;

        gemm_mfma<<<dim3(ND3 / 128, TT / 128), 256, 0, stream>>>(Abf[l], WTl, xp);

        it0_kernel<<<TT, 256, 0, stream>>>(xp, Whl, bhl, h0 + (size_t)l * DD, term,
                                           Hb0, Hbf0, ybf, yf32, finals,
                                           g_start, g_perm, g_nact);

        phaseb_kernel<<<NBLK, 512, 0, stream>>>(
            Hb0, Hb1, Hbf0, Hbf1, xp, WhTl, bhl, ybf, yf32, finals,
            g_start, g_perm, g_nact,
            barws + (size_t)l * (MAXIT - 1) * BSLOT);

        float* Hlast = ((MAXIT - 1) & 1) ? Hb1 : Hb0;
        cleanup_kernel<<<64, 256, 0, stream>>>(Hlast, xp, Whl, bhl, ybf, yf32,
                                               finals, g_start, g_len, g_perm,
                                               g_nact);
    }
}